// Round 2
// 563.000 us; speedup vs baseline: 1.2389x; 1.2389x over previous
//
#include <hip/hip_runtime.h>
#include <hip/hip_bf16.h>

// Self_mask_Spectral_MSA on MI355X — Round 5 resubmit (R5 bench was an infra failure:
// "MI355X container failed twice", no compile/pytest/counter evidence against the kernel).
// B=4, H=W=256, C=32, heads=4, d=8. f32 I/O, fp32 accumulation, bf16 intermediates.
//
// R5 changes vs R4 (passed, 697us, absmax 0.0156):
//  - pos1/pos2 (131+~125us, VALU-bound at 26% FMA efficiency, MfmaUtil=0) rewritten as
//    LDS-free MFMA kernels: conv3x3 32->32 = 9 taps x 2 ch-tiles of mfma_f32_16x16x32_bf16.
//    A = weights [r][o][i] (k-contiguous 8 per lane), B = input pixels [n][c] bf16
//    (one predicated dwordx4 per lane per tap), D layout col=pixel row=channel.
//    pos2's M@vspec epilogue = 2 more MFMAs (M pre-rounded to bf16).
//  - pre_kernel also emits [r][o][i] bf16 weights (wA1/wA2); mid_kernel also emits bf16 M.
//  - R3's fused pos_out fallback kept unchanged for small-ws case.

#define NB 4
#define NC 32
#define NS 256
#define NN 65536

typedef unsigned short u16;
typedef unsigned int u32;
typedef __bf16 bf16x8 __attribute__((ext_vector_type(8)));
typedef float f32x4 __attribute__((ext_vector_type(4)));

__device__ __forceinline__ float bf2f(u16 s){ return __uint_as_float(((u32)s) << 16); }
__device__ __forceinline__ u16 f2bf(float x){
  u32 u = __float_as_uint(x);
  u32 r = (u + 0x7fffu + ((u >> 16) & 1u)) >> 16;   // RNE
  return (u16)r;
}
__device__ __forceinline__ void dec8(uint4 u, float* f){
  f[0] = __uint_as_float((u.x & 0xffffu) << 16);
  f[1] = __uint_as_float(u.x & 0xffff0000u);
  f[2] = __uint_as_float((u.y & 0xffffu) << 16);
  f[3] = __uint_as_float(u.y & 0xffff0000u);
  f[4] = __uint_as_float((u.z & 0xffffu) << 16);
  f[5] = __uint_as_float(u.z & 0xffff0000u);
  f[6] = __uint_as_float((u.w & 0xffffu) << 16);
  f[7] = __uint_as_float(u.w & 0xffff0000u);
}
__device__ __forceinline__ void ld32f(const float* __restrict__ p, float* x){
  const float4* q = (const float4*)p;
  #pragma unroll
  for (int k = 0; k < 8; k++){
    float4 f = q[k];
    x[4 * k] = f.x; x[4 * k + 1] = f.y; x[4 * k + 2] = f.z; x[4 * k + 3] = f.w;
  }
}
__device__ __forceinline__ uint4 pack8(const float* f){
  uint4 u;
  u.x = (u32)f2bf(f[0]) | ((u32)f2bf(f[1]) << 16);
  u.y = (u32)f2bf(f[2]) | ((u32)f2bf(f[3]) << 16);
  u.z = (u32)f2bf(f[4]) | ((u32)f2bf(f[5]) << 16);
  u.w = (u32)f2bf(f[6]) | ((u32)f2bf(f[7]) << 16);
  return u;
}
__device__ __forceinline__ float gelu_exact(float x){
  return 0.5f * x * (1.0f + erff(x * 0.70710678118654752f));
}
__device__ __forceinline__ float sigmoidf_(float x){ return 1.0f / (1.0f + expf(-x)); }

// ---------------------- pre: zero accumulators + fold SA weights + transpose pos weights
__global__ __launch_bounds__(256) void pre_kernel(
    const float* __restrict__ c1a, const float* __restrict__ c1b,
    const float* __restrict__ c2a, const float* __restrict__ c2b,
    const float* __restrict__ p1, const float* __restrict__ p2,
    float* __restrict__ zbase, float* __restrict__ W1, float* __restrict__ W2,
    u16* __restrict__ wt1, u16* __restrict__ wt2,
    u16* __restrict__ wA1, u16* __restrict__ wA2){
  int t = threadIdx.x;
  for (int i = t; i < 1408; i += 256) zbase[i] = 0.f;          // sums(128) + gacc(1280)
  for (int idx = t; idx < 288; idx += 256){                    // W1[r*32+j]
    int r = idx >> 5, j = idx & 31;
    float s = 0.f;
    for (int i = 0; i < 32; i++) s += c1b[i] * c1a[(i * 32 + j) * 9 + r];
    W1[idx] = s;
  }
  for (int idx = t; idx < 1568; idx += 256){                   // W2[r*32+j]
    int r = idx >> 5, j = idx & 31;
    float s = 0.f;
    for (int i = 0; i < 32; i++) s += c2b[i] * c2a[(i * 32 + j) * 49 + r];
    W2[idx] = s;
  }
  for (int idx = t; idx < 9216; idx += 256){                   // OIHW -> layouts
    int o = idx / 288;
    int rem = idx - o * 288;
    int i = rem / 9;
    int r = rem - i * 9;
    u16 w1v = f2bf(p1[idx]);
    u16 w2v = f2bf(p2[idx]);
    wt1[(r * 32 + i) * 32 + o] = w1v;      // [r][i][o]  (fallback path)
    wt2[(r * 32 + i) * 32 + o] = w2v;
    wA1[(r * 32 + o) * 32 + i] = w1v;      // [r][o][i]  (MFMA A-fragments)
    wA2[(r * 32 + o) * 32 + i] = w2v;
  }
}

// ---------------------------------------------------------------- channel sums
__global__ __launch_bounds__(256) void channel_sum_kernel(const float* __restrict__ xhsi,
                                                          float* __restrict__ sums){
  int b = blockIdx.x >> 6;
  int blk = blockIdx.x & 63;
  const float* p = xhsi + (size_t)b * NN * NC;
  int t = threadIdx.x;
  int base = blk * 32768;
  float acc = 0.f;
  for (int k = 0; k < 128; k++) acc += p[base + t + k * 256];
  __shared__ float red[256];
  red[t] = acc;
  __syncthreads();
  if (t < 32){
    float s = 0.f;
    #pragma unroll
    for (int k = 0; k < 8; k++) s += red[t + k * 32];     // channel of red[j] is j&31
    atomicAdd(&sums[b * 32 + t], s);
  }
}

// ----------------- mid: channel mask (sigmoid MLP) + attention softmax + M fold
__global__ __launch_bounds__(256) void mid_kernel(
    const float* __restrict__ sums, const float* __restrict__ fc1,
    const float* __restrict__ fc2, float* __restrict__ cmaskf, float* __restrict__ out_cm,
    const float* __restrict__ gacc, const float* __restrict__ projW, float* __restrict__ Mf,
    u16* __restrict__ Mbf){
  __shared__ float avg[NB][NC], hid[NB][NC];
  __shared__ float attn_s[16][64];
  int t = threadIdx.x;
  if (t < 128){
    int b = t >> 5, o = t & 31;
    avg[b][o] = sums[t] * (1.0f / 65536.0f);
  }
  __syncthreads();
  if (t < 128){
    int b = t >> 5, o = t & 31;
    float s = 0.f;
    for (int j = 0; j < 32; j++) s += fc1[o * 32 + j] * avg[b][j];
    hid[b][o] = fmaxf(s, 0.f);
  }
  // attention: softmax over normalized gram (independent of channel-mask path)
  if (t < 128){
    int bh = t >> 3, d = t & 7;   // bh = b*4+h
    int b = bh >> 2, h = bh & 3;
    const float* base = gacc + b * 320;
    int o = h * 8 + d;
    float nk = fmaxf(sqrtf(base[256 + o]), 1e-12f);
    float l[8];
    float mx = -1e30f;
    #pragma unroll
    for (int e = 0; e < 8; e++){
      float nq = fmaxf(sqrtf(base[288 + h * 8 + e]), 1e-12f);
      l[e] = base[o * 8 + e] / (nk * nq);
      mx = fmaxf(mx, l[e]);
    }
    float se = 0.f;
    #pragma unroll
    for (int e = 0; e < 8; e++){ l[e] = expf(l[e] - mx); se += l[e]; }
    float inv = 1.f / se;
    #pragma unroll
    for (int e = 0; e < 8; e++) attn_s[bh][d * 8 + e] = l[e] * inv;
  }
  __syncthreads();
  if (t < 128){
    int b = t >> 5, o = t & 31;
    float s2 = 0.f;
    for (int i = 0; i < 32; i++) s2 += fc2[o * 32 + i] * hid[b][i];
    float m = sigmoidf_(s2);
    cmaskf[t] = m;
    out_cm[t] = m;
  }
  for (int idx = t; idx < 4096; idx += 256){        // M[b][o][i]
    int b = idx >> 10, o = (idx >> 5) & 31, i = idx & 31;
    int hd = i >> 3, e = i & 7;
    float s = 0.f;
    #pragma unroll
    for (int d = 0; d < 8; d++)
      s += projW[o * 32 + hd * 8 + d] * attn_s[b * 4 + hd][d * 8 + e];
    Mf[idx] = s;
    Mbf[idx] = f2bf(s);
  }
}

// tile: [c8][xl][yl] uint4 (8 bf16 channels per uint4). 16x16 output px, halo 3.
__global__ __launch_bounds__(256) void spatial_mask_kernel(
    const float* __restrict__ xmsi, const float* __restrict__ W1, const float* __restrict__ W2,
    const float* __restrict__ sac3, float* __restrict__ out_sm){
  __shared__ uint4 tile[4][22][25];
  __shared__ float W1s[9 * 32], W2s[49 * 32];
  int t = threadIdx.x;
  int b = blockIdx.z;
  int x0 = blockIdx.x * 16, y0 = blockIdx.y * 16;
  for (int idx = t; idx < 9 * 32;  idx += 256) W1s[idx] = W1[idx];
  for (int idx = t; idx < 49 * 32; idx += 256) W2s[idx] = W2[idx];
  for (int p = t; p < 484; p += 256){
    int xl = p / 22, yl = p - xl * 22;
    int X = x0 - 3 + xl, Y = y0 - 3 + yl;
    uint4 u0, u1, u2, u3;
    if (X >= 0 && X < NS && Y >= 0 && Y < NS){
      float xr[32];
      ld32f(xmsi + ((size_t)b * NN + (size_t)Y * NS + X) * NC, xr);
      u0 = pack8(xr); u1 = pack8(xr + 8); u2 = pack8(xr + 16); u3 = pack8(xr + 24);
    } else {
      u0 = u1 = u2 = u3 = make_uint4(0, 0, 0, 0);
    }
    tile[0][xl][yl] = u0; tile[1][xl][yl] = u1; tile[2][xl][yl] = u2; tile[3][xl][yl] = u3;
  }
  __syncthreads();
  int j = t & 15, i = t >> 4;     // j: y (h), i: x (w)
  float m1 = 0.f, m2 = 0.f;
  for (int aw = 0; aw < 7; aw++){
    for (int ah = 0; ah < 7; ah++){
      const float* wr = &W2s[(aw * 7 + ah) * 32];
      float s = 0.f;
      #pragma unroll
      for (int c = 0; c < 4; c++){
        uint4 u = tile[c][i + aw][j + ah];
        float g[8]; dec8(u, g);
        #pragma unroll
        for (int k = 0; k < 8; k++) s += g[k] * wr[c * 8 + k];
      }
      m2 += s;
    }
  }
  for (int aw = 0; aw < 3; aw++){
    for (int ah = 0; ah < 3; ah++){
      const float* wr = &W1s[(aw * 3 + ah) * 32];
      float s = 0.f;
      #pragma unroll
      for (int c = 0; c < 4; c++){
        uint4 u = tile[c][i + aw + 2][j + ah + 2];
        float g[8]; dec8(u, g);
        #pragma unroll
        for (int k = 0; k < 8; k++) s += g[k] * wr[c * 8 + k];
      }
      m1 += s;
    }
  }
  float m = sac3[0] * m1 + sac3[1] * m2;
  float sg = sigmoidf_(m);
  int x = x0 + i, y = y0 + j;
  out_sm[(size_t)b * NN + (size_t)x * NS + y] = sg;   // (b,1,w,h): w-major
}

// ---------------------------------------------------- fused q/k projection + gram
__global__ __launch_bounds__(256) void qk_gram_kernel(const float* __restrict__ xfu,
                                                      const float* __restrict__ Wq,
                                                      const float* __restrict__ Wk,
                                                      float* __restrict__ gacc){
  int t = threadIdx.x;
  int wv = t >> 6, lane = t & 63;
  int role = lane >> 5;           // 0: q, 1: k
  int o = lane & 31;
  const float* W = role ? Wk : Wq;
  float w[32];
  ld32f(W + o * 32, w);
  float Gacc[8];
  #pragma unroll
  for (int e = 0; e < 8; e++) Gacc[e] = 0.f;
  float nrm = 0.f;
  int base = blockIdx.x * 512 + wv * 128;
  int b = blockIdx.x >> 7;        // 128 blocks per batch
  for (int r = 0; r < 128; r++){
    int row = base + r;
    float xr[32];
    ld32f(xfu + (size_t)row * NC, xr);
    float s = 0.f;
    #pragma unroll
    for (int i2 = 0; i2 < 32; i2++) s += xr[i2] * w[i2];
    nrm += s * s;
    #pragma unroll
    for (int e = 0; e < 8; e++){
      float qe = __shfl(s, (o & 24) + e, 64);   // q-lane of same head, same row
      Gacc[e] += s * qe;                        // meaningful on k-lanes only
    }
  }
  __shared__ float LG[4][32][8];
  __shared__ float Lk[4][32], Lq[4][32];
  if (role){
    #pragma unroll
    for (int e = 0; e < 8; e++) LG[wv][o][e] = Gacc[e];
    Lk[wv][o] = nrm;
  } else {
    Lq[wv][o] = nrm;
  }
  __syncthreads();
  {
    int oo = t >> 3, ee = t & 7;
    float s4 = LG[0][oo][ee] + LG[1][oo][ee] + LG[2][oo][ee] + LG[3][oo][ee];
    atomicAdd(&gacc[b * 320 + t], s4);
  }
  if (t < 32){
    atomicAdd(&gacc[b * 320 + 256 + t], Lk[0][t] + Lk[1][t] + Lk[2][t] + Lk[3][t]);
  } else if (t < 64){
    int oo = t - 32;
    atomicAdd(&gacc[b * 320 + 288 + oo], Lq[0][oo] + Lq[1][oo] + Lq[2][oo] + Lq[3][oo]);
  }
}

// --------------------------------------------- vspec: fused V-proj + gate + conv + residual
__global__ __launch_bounds__(256) void vspec_kernel(
    const float* __restrict__ xfu, const float* __restrict__ Wv,
    const float* __restrict__ attnW, const float* __restrict__ out_sm,
    const float* __restrict__ cmaskf, const float* __restrict__ xhsi,
    u16* __restrict__ vspec_g){
  __shared__ u16 gv[32 * 10 * 40];              // [c][xl][yl(34,pad40)] gated v, bf16
  __shared__ u16 Wl[9 * 32 * 32];               // [r][i][o] bf16, r = aw*3+ah
  __shared__ alignas(16) float WvL[1024];       // [i][o]
  __shared__ float cml[32];
  int t = threadIdx.x;
  int b = blockIdx.z;
  int x0 = blockIdx.x * 8, y0 = blockIdx.y * 32;

  for (int idx = t; idx < 1024; idx += 256){
    int oo = idx >> 5, ii = idx & 31;
    WvL[ii * 32 + oo] = Wv[idx];                // Wv[o][i] -> [i][o]
  }
  if (t < 32) cml[t] = cmaskf[b * 32 + t];
  __syncthreads();

  for (int idx = t; idx < 9216; idx += 256){
    int oo = idx / 288;
    int rem = idx - oo * 288;
    int ii = rem / 9;
    int r = rem - ii * 9;
    Wl[(r * 32 + ii) * 32 + oo] = f2bf(attnW[idx]);
  }
  for (int p = t; p < 340; p += 256){           // 10 x 34 halo tile
    int xl = p / 34, yl = p - xl * 34;
    int X = x0 - 1 + xl, Y = y0 - 1 + yl;       // X: w, Y: h
    u16* dst = &gv[xl * 40 + yl];               // + c*400 per channel
    if (X >= 0 && X < NS && Y >= 0 && Y < NS){
      float xr[32];
      ld32f(xfu + ((size_t)b * NN + (size_t)Y * NS + X) * NC, xr);
      float sm = out_sm[(size_t)b * NN + (size_t)X * NS + Y];
      float vo[32];
      #pragma unroll
      for (int q = 0; q < 32; q++) vo[q] = 0.f;
      for (int i = 0; i < 32; i++){
        const float4* wr = (const float4*)&WvL[i * 32];
        float xv = xr[i];
        #pragma unroll
        for (int q = 0; q < 8; q++){
          float4 w4 = wr[q];
          vo[4 * q]     += xv * w4.x;
          vo[4 * q + 1] += xv * w4.y;
          vo[4 * q + 2] += xv * w4.z;
          vo[4 * q + 3] += xv * w4.w;
        }
      }
      #pragma unroll
      for (int c = 0; c < 32; c++) dst[c * 400] = f2bf(vo[c] * sm * cml[c]);
    } else {
      #pragma unroll
      for (int c = 0; c < 32; c++) dst[c * 400] = 0;
    }
  }
  __syncthreads();

  int o = t & 31, xs = t >> 5;
  float acc[32];
  #pragma unroll
  for (int yy = 0; yy < 32; yy++) acc[yy] = 0.f;
  #pragma unroll
  for (int aw = 0; aw < 3; aw++){
    for (int i2 = 0; i2 < 32; i2++){
      const uint4* rp = (const uint4*)(gv + (i2 * 10 + xs + aw) * 40);
      uint4 r0 = rp[0], r1 = rp[1], r2 = rp[2], r3 = rp[3], r4 = rp[4];
      float g[40];
      dec8(r0, g); dec8(r1, g + 8); dec8(r2, g + 16); dec8(r3, g + 24); dec8(r4, g + 32);
      const int wb = (aw * 3 * 32 + i2) * 32 + o;
      float w0 = bf2f(Wl[wb]);
      float w1 = bf2f(Wl[wb + 1024]);
      float w2 = bf2f(Wl[wb + 2048]);
      #pragma unroll
      for (int yy = 0; yy < 32; yy++)
        acc[yy] = fmaf(g[yy], w0, fmaf(g[yy + 1], w1, fmaf(g[yy + 2], w2, acc[yy])));
    }
  }
  int x = x0 + xs;
  #pragma unroll
  for (int yy = 0; yy < 32; yy++){
    size_t n = (size_t)b * NN + (size_t)(y0 + yy) * NS + x;
    vspec_g[n * NC + o] = f2bf(acc[yy] + xhsi[n * NC + o]);
  }
}

// ------------------------- SPLIT PATH R5: MFMA pos1 (vspec -> t), no LDS
// Wave handles 4 groups of 16 consecutive X at fixed Y. A=W[r][o][i], B=vspec px.
__global__ __launch_bounds__(256) void pos1_mfma_kernel(
    const u16* __restrict__ vspec_g, const u16* __restrict__ wA,
    const float* __restrict__ pos1b, u16* __restrict__ t_g){
  int t = threadIdx.x;
  int wv = t >> 6, l = t & 63;
  int lp = l & 15, lk = l >> 4;                 // fragment pixel / k-chunk
  int b = blockIdx.x >> 8, Y = blockIdx.x & 255;

  bf16x8 wf[9][2];
  #pragma unroll
  for (int r = 0; r < 9; r++){
    wf[r][0] = *(const bf16x8*)(wA + ((r * 32 + lp) * 32 + lk * 8));
    wf[r][1] = *(const bf16x8*)(wA + ((r * 32 + 16 + lp) * 32 + lk * 8));
  }
  float bs[8];
  #pragma unroll
  for (int j = 0; j < 4; j++){
    bs[j]     = pos1b[lk * 4 + j];
    bs[4 + j] = pos1b[16 + lk * 4 + j];
  }

  const u16* src = vspec_g + (size_t)b * NN * NC;
  u16* dst = t_g + (size_t)b * NN * NC;

  for (int g = 0; g < 4; g++){
    int X0 = wv * 64 + g * 16;
    f32x4 acc0 = {0.f, 0.f, 0.f, 0.f};
    f32x4 acc1 = {0.f, 0.f, 0.f, 0.f};
    #pragma unroll
    for (int dh = -1; dh <= 1; dh++){
      int Yi = Y + dh;
      if ((unsigned)Yi < NS){                   // uniform skip = zero-pad rows
        const u16* row = src + (size_t)Yi * (NS * NC) + lk * 8;
        #pragma unroll
        for (int dw = -1; dw <= 1; dw++){
          int Xi = X0 + lp + dw;
          uint4 u = make_uint4(0, 0, 0, 0);
          if (dw == 0 || (unsigned)Xi < NS) u = *(const uint4*)(row + Xi * NC);
          bf16x8 bfr = __builtin_bit_cast(bf16x8, u);
          const int r = (dw + 1) * 3 + (dh + 1);
          acc0 = __builtin_amdgcn_mfma_f32_16x16x32_bf16(wf[r][0], bfr, acc0, 0, 0, 0);
          acc1 = __builtin_amdgcn_mfma_f32_16x16x32_bf16(wf[r][1], bfr, acc1, 0, 0, 0);
        }
      }
    }
    // D: col=lp=pixel, rows = lk*4+j (+16 for tile 1) = out channel
    float v0 = gelu_exact(acc0.x + bs[0]);
    float v1 = gelu_exact(acc0.y + bs[1]);
    float v2 = gelu_exact(acc0.z + bs[2]);
    float v3 = gelu_exact(acc0.w + bs[3]);
    float v4 = gelu_exact(acc1.x + bs[4]);
    float v5 = gelu_exact(acc1.y + bs[5]);
    float v6 = gelu_exact(acc1.z + bs[6]);
    float v7 = gelu_exact(acc1.w + bs[7]);
    u16* dp = dst + ((size_t)Y * NS + (X0 + lp)) * NC + lk * 4;
    *(uint2*)dp = make_uint2((u32)f2bf(v0) | ((u32)f2bf(v1) << 16),
                             (u32)f2bf(v2) | ((u32)f2bf(v3) << 16));
    *(uint2*)(dp + 16) = make_uint2((u32)f2bf(v4) | ((u32)f2bf(v5) << 16),
                                    (u32)f2bf(v6) | ((u32)f2bf(v7) << 16));
  }
}

// -------------------- SPLIT PATH R5: MFMA pos2 (t -> out, + out1 epilogue), no LDS
// Wave handles 4 groups of 16 consecutive Y at fixed X (store (b,c,w,h) coalesced in h).
__global__ __launch_bounds__(256) void pos2_mfma_kernel(
    const u16* __restrict__ t_g, const u16* __restrict__ vspec_g,
    const u16* __restrict__ wA, const float* __restrict__ pos2b,
    const u16* __restrict__ Mbf, const float* __restrict__ projb,
    float* __restrict__ outp){
  int t = threadIdx.x;
  int wv = t >> 6, l = t & 63;
  int lp = l & 15, lk = l >> 4;
  int b = blockIdx.x >> 8, X = blockIdx.x & 255;

  bf16x8 wf[9][2];
  #pragma unroll
  for (int r = 0; r < 9; r++){
    wf[r][0] = *(const bf16x8*)(wA + ((r * 32 + lp) * 32 + lk * 8));
    wf[r][1] = *(const bf16x8*)(wA + ((r * 32 + 16 + lp) * 32 + lk * 8));
  }
  bf16x8 mf0 = *(const bf16x8*)(Mbf + ((b * 32 + lp) * 32 + lk * 8));
  bf16x8 mf1 = *(const bf16x8*)(Mbf + ((b * 32 + 16 + lp) * 32 + lk * 8));
  float b2s[8], pbs[8];
  #pragma unroll
  for (int j = 0; j < 4; j++){
    b2s[j]     = pos2b[lk * 4 + j];
    b2s[4 + j] = pos2b[16 + lk * 4 + j];
    pbs[j]     = projb[lk * 4 + j];
    pbs[4 + j] = projb[16 + lk * 4 + j];
  }

  const u16* tsrc = t_g + (size_t)b * NN * NC;
  const u16* vsrc = vspec_g + (size_t)b * NN * NC;
  float* ob0 = outp + (size_t)b * 32 * NN + (size_t)X * NS;

  for (int g = 0; g < 4; g++){
    int Y0 = wv * 64 + g * 16;
    int Yp = Y0 + lp;
    // epilogue GEMM first (independent chain): P = M @ vspec[px]
    f32x4 e0 = {0.f, 0.f, 0.f, 0.f};
    f32x4 e1 = {0.f, 0.f, 0.f, 0.f};
    {
      uint4 u = *(const uint4*)(vsrc + ((size_t)Yp * NS + X) * NC + lk * 8);
      bf16x8 bfr = __builtin_bit_cast(bf16x8, u);
      e0 = __builtin_amdgcn_mfma_f32_16x16x32_bf16(mf0, bfr, e0, 0, 0, 0);
      e1 = __builtin_amdgcn_mfma_f32_16x16x32_bf16(mf1, bfr, e1, 0, 0, 0);
    }
    f32x4 acc0 = {0.f, 0.f, 0.f, 0.f};
    f32x4 acc1 = {0.f, 0.f, 0.f, 0.f};
    #pragma unroll
    for (int dw = -1; dw <= 1; dw++){
      int Xi = X + dw;
      if ((unsigned)Xi < NS){                   // uniform skip = zero-pad cols
        const u16* col = tsrc + (size_t)Xi * NC + lk * 8;
        #pragma unroll
        for (int dh = -1; dh <= 1; dh++){
          int Yi = Yp + dh;
          uint4 u = make_uint4(0, 0, 0, 0);
          if (dh == 0 || (unsigned)Yi < NS) u = *(const uint4*)(col + (size_t)Yi * (NS * NC));
          bf16x8 bfr = __builtin_bit_cast(bf16x8, u);
          const int r = (dw + 1) * 3 + (dh + 1);
          acc0 = __builtin_amdgcn_mfma_f32_16x16x32_bf16(wf[r][0], bfr, acc0, 0, 0, 0);
          acc1 = __builtin_amdgcn_mfma_f32_16x16x32_bf16(wf[r][1], bfr, acc1, 0, 0, 0);
        }
      }
    }
    float r0 = acc0.x + b2s[0] + gelu_exact(e0.x + pbs[0]);
    float r1 = acc0.y + b2s[1] + gelu_exact(e0.y + pbs[1]);
    float r2 = acc0.z + b2s[2] + gelu_exact(e0.z + pbs[2]);
    float r3 = acc0.w + b2s[3] + gelu_exact(e0.w + pbs[3]);
    float r4 = acc1.x + b2s[4] + gelu_exact(e1.x + pbs[4]);
    float r5 = acc1.y + b2s[5] + gelu_exact(e1.y + pbs[5]);
    float r6 = acc1.z + b2s[6] + gelu_exact(e1.z + pbs[6]);
    float r7 = acc1.w + b2s[7] + gelu_exact(e1.w + pbs[7]);
    float* ob = ob0 + Yp + (size_t)(lk * 4) * NN;   // channel lk*4, + c*NN per channel
    ob[0]                 = r0;
    ob[(size_t)NN]        = r1;
    ob[(size_t)2 * NN]    = r2;
    ob[(size_t)3 * NN]    = r3;
    float* ob2 = ob + (size_t)16 * NN;
    ob2[0]                = r4;
    ob2[(size_t)NN]       = r5;
    ob2[(size_t)2 * NN]   = r6;
    ob2[(size_t)3 * NN]   = r7;
  }
}

// ------------------------- FALLBACK PATH (ws too small): R3's fused pos_out, proven
__global__ __launch_bounds__(320) void pos_out_kernel(
    const u16* __restrict__ vspec_g, const u16* __restrict__ wt1,
    const u16* __restrict__ wt2, const float* __restrict__ pos1b,
    const float* __restrict__ pos2b, const float* __restrict__ Mf,
    const float* __restrict__ projb, float* __restrict__ outp){
  __shared__ u16 vs[32 * 12 * 40];    // [i][vxl(12)][vyl(36,pad40)]
  __shared__ u16 tt[32 * 10 * 40];    // [o][txl(10)][tyl(34,pad40)]
  __shared__ u16 wsl[3072];           // one aw-slice: [ah][i][o]
  int t = threadIdx.x;
  int b = blockIdx.z;
  int x0 = blockIdx.x * 8, y0 = blockIdx.y * 32;
  int o = t & 31, xsl = t >> 5;       // xsl in [0,10)

  for (int p = t; p < 12 * 36; p += 320){
    int vxl = p / 36, vyl = p - vxl * 36;
    int X = x0 - 2 + vxl, Y = y0 - 2 + vyl;
    u16* dst = &vs[vxl * 40 + vyl];
    if (X >= 0 && X < NS && Y >= 0 && Y < NS){
      const uint4* src = (const uint4*)(vspec_g + ((size_t)b * NN + (size_t)Y * NS + X) * NC);
      uint4 u0 = src[0], u1 = src[1], u2 = src[2], u3 = src[3];
      alignas(16) u16 raw[32];
      *(uint4*)(raw) = u0; *(uint4*)(raw + 8) = u1;
      *(uint4*)(raw + 16) = u2; *(uint4*)(raw + 24) = u3;
      #pragma unroll
      for (int i = 0; i < 32; i++) dst[i * 480] = raw[i];
    } else {
      #pragma unroll
      for (int i = 0; i < 32; i++) dst[i * 480] = 0;
    }
  }
  __syncthreads();

  float ta[34];
  #pragma unroll
  for (int k = 0; k < 34; k++) ta[k] = 0.f;
  for (int aw = 0; aw < 3; aw++){
    for (int idx = t; idx < 3072; idx += 320) wsl[idx] = wt1[aw * 3072 + idx];
    __syncthreads();
    for (int i2 = 0; i2 < 32; i2++){
      const uint4* rp = (const uint4*)(vs + (i2 * 12 + xsl + aw) * 40);
      uint4 r0 = rp[0], r1 = rp[1], r2 = rp[2], r3 = rp[3], r4 = rp[4];
      float g[40];
      dec8(r0, g); dec8(r1, g + 8); dec8(r2, g + 16); dec8(r3, g + 24); dec8(r4, g + 32);
      float w0 = bf2f(wsl[i2 * 32 + o]);
      float w1 = bf2f(wsl[i2 * 32 + o + 1024]);
      float w2 = bf2f(wsl[i2 * 32 + o + 2048]);
      #pragma unroll
      for (int yl = 0; yl < 34; yl++)
        ta[yl] = fmaf(g[yl], w0, fmaf(g[yl + 1], w1, fmaf(g[yl + 2], w2, ta[yl])));
    }
    __syncthreads();
  }
  {
    float b1 = pos1b[o];
    int X = x0 - 1 + xsl;
    bool colOK = (X >= 0 && X < NS);
    u16* trow = &tt[(o * 10 + xsl) * 40];
    #pragma unroll
    for (int yl = 0; yl < 34; yl++){
      int Y = y0 - 1 + yl;
      float val = (colOK && Y >= 0 && Y < NS) ? gelu_exact(ta[yl] + b1) : 0.f;
      trow[yl] = f2bf(val);
    }
  }
  __syncthreads();

  float acc2[32];
  #pragma unroll
  for (int yy = 0; yy < 32; yy++) acc2[yy] = 0.f;
  for (int aw = 0; aw < 3; aw++){
    for (int idx = t; idx < 3072; idx += 320) wsl[idx] = wt2[aw * 3072 + idx];
    __syncthreads();
    if (xsl < 8){
      for (int i2 = 0; i2 < 32; i2++){
        const uint4* rp = (const uint4*)(tt + (i2 * 10 + xsl + aw) * 40);
        uint4 r0 = rp[0], r1 = rp[1], r2 = rp[2], r3 = rp[3], r4 = rp[4];
        float g[40];
        dec8(r0, g); dec8(r1, g + 8); dec8(r2, g + 16); dec8(r3, g + 24); dec8(r4, g + 32);
        float w0 = bf2f(wsl[i2 * 32 + o]);
        float w1 = bf2f(wsl[i2 * 32 + o + 1024]);
        float w2 = bf2f(wsl[i2 * 32 + o + 2048]);
        #pragma unroll
        for (int yy = 0; yy < 32; yy++)
          acc2[yy] = fmaf(g[yy], w0, fmaf(g[yy + 1], w1, fmaf(g[yy + 2], w2, acc2[yy])));
      }
    }
    __syncthreads();
  }
  if (xsl < 8){
    int x = x0 + xsl;
    float m[32];
    {
      const float4* mp = (const float4*)(Mf + b * 1024 + o * 32);
      #pragma unroll
      for (int k = 0; k < 8; k++){
        float4 f = mp[k];
        m[4 * k] = f.x; m[4 * k + 1] = f.y; m[4 * k + 2] = f.z; m[4 * k + 3] = f.w;
      }
    }
    float pb = projb[o];
    float b2v = pos2b[o];
    float outv[32];
    #pragma unroll
    for (int yy = 0; yy < 32; yy++){
      size_t n = (size_t)b * NN + (size_t)(y0 + yy) * NS + x;
      const uint4* xp = (const uint4*)(vspec_g + n * NC);
      uint4 u0 = xp[0], u1 = xp[1], u2 = xp[2], u3 = xp[3];
      float xr[32];
      dec8(u0, xr); dec8(u1, xr + 8); dec8(u2, xr + 16); dec8(u3, xr + 24);
      float s = pb;
      #pragma unroll
      for (int i2 = 0; i2 < 32; i2++) s += m[i2] * xr[i2];
      outv[yy] = acc2[yy] + b2v + gelu_exact(s);
    }
    float4* dp = (float4*)(outp + (((size_t)(b * 32 + o) * NS) + x) * NS + y0);
    #pragma unroll
    for (int k = 0; k < 8; k++)
      dp[k] = make_float4(outv[4 * k], outv[4 * k + 1], outv[4 * k + 2], outv[4 * k + 3]);
  }
}

// ---------------------------------------------------------------------- launch
extern "C" void kernel_launch(void* const* d_in, const int* in_sizes, int n_in,
                              void* d_out, int out_size, void* d_ws, size_t ws_size,
                              hipStream_t stream){
  (void)in_sizes; (void)n_in; (void)out_size;
  const float* xfu   = (const float*)d_in[0];
  const float* xmsi  = (const float*)d_in[1];
  const float* xhsi  = (const float*)d_in[2];
  const float* Wq    = (const float*)d_in[3];
  const float* Wk    = (const float*)d_in[4];
  const float* Wv    = (const float*)d_in[5];
  const float* projW = (const float*)d_in[6];
  const float* projb = (const float*)d_in[7];
  const float* pos1W = (const float*)d_in[8];
  const float* pos1b = (const float*)d_in[9];
  const float* pos2W = (const float*)d_in[10];
  const float* pos2b = (const float*)d_in[11];
  const float* cafc1 = (const float*)d_in[12];
  const float* cafc2 = (const float*)d_in[13];
  const float* sac1a = (const float*)d_in[14];
  const float* sac1b = (const float*)d_in[15];
  const float* sac2a = (const float*)d_in[16];
  const float* sac2b = (const float*)d_in[17];
  const float* sac3  = (const float*)d_in[18];
  const float* attnW = (const float*)d_in[19];

  float* out = (float*)d_out;
  float* out_main = out;                  // (b,c,w,h) 8388608 f32
  float* out_cm   = out + 8388608;        // 128
  float* out_sm   = out + 8388736;        // 262144

  // workspace map: small [0,32K), wt [32K,70K), wA/Mbf [70K,115K), vspec [128K,+16M), t [+16M,+32M)
  char* ws = (char*)d_ws;
  float* sums   = (float*)(ws + 0);         // 128 f   (zeroed with gacc: 1408 f total)
  float* gacc   = (float*)(ws + 512);       // 1280 f
  float* cmaskf = (float*)(ws + 5632);      // 128 f
  float* W1     = (float*)(ws + 6144);      // 288 f
  float* W2     = (float*)(ws + 7296);      // 1568 f
  float* Mf     = (float*)(ws + 16384);     // 4096 f
  u16*   wt1    = (u16*)(ws + 32768);       // 9216 bf16 [r][i][o] (fallback)
  u16*   wt2    = (u16*)(ws + 51200);       // 9216 bf16
  u16*   wA1    = (u16*)(ws + 69632);       // 9216 bf16 [r][o][i] (MFMA)
  u16*   wA2    = (u16*)(ws + 88064);       // 9216 bf16
  u16*   Mbf    = (u16*)(ws + 106496);      // 4096 bf16 [b][o][i]
  u16*   vspec  = (u16*)(ws + 131072);      // 16 MB bf16 (b,n,c)
  u16*   t_g    = (u16*)(ws + 131072 + 16777216);   // 16 MB bf16 (split path only)
  const bool split = ws_size >= (size_t)(131072 + 2 * 16777216);

  pre_kernel<<<1, 256, 0, stream>>>(sac1a, sac1b, sac2a, sac2b, pos1W, pos2W,
                                    sums, W1, W2, wt1, wt2, wA1, wA2);
  channel_sum_kernel<<<256, 256, 0, stream>>>(xhsi, sums);
  spatial_mask_kernel<<<dim3(16, 16, NB), 256, 0, stream>>>(xmsi, W1, W2, sac3, out_sm);
  qk_gram_kernel<<<512, 256, 0, stream>>>(xfu, Wq, Wk, gacc);
  mid_kernel<<<1, 256, 0, stream>>>(sums, cafc1, cafc2, cmaskf, out_cm, gacc, projW, Mf, Mbf);
  vspec_kernel<<<dim3(32, 8, NB), 256, 0, stream>>>(
      xfu, Wv, attnW, out_sm, cmaskf, xhsi, vspec);
  if (split){
    pos1_mfma_kernel<<<1024, 256, 0, stream>>>(vspec, wA1, pos1b, t_g);
    pos2_mfma_kernel<<<1024, 256, 0, stream>>>(t_g, vspec, wA2, pos2b, Mbf, projb, out_main);
  } else {
    pos_out_kernel<<<dim3(32, 8, NB), 320, 0, stream>>>(
        vspec, wt1, wt2, pos1b, pos2b, Mf, projb, out_main);
  }
}

// Round 3
// 497.257 us; speedup vs baseline: 1.4027x; 1.1322x over previous
//
#include <hip/hip_runtime.h>
#include <hip/hip_bf16.h>

// Self_mask_Spectral_MSA on MI355X — Round 6: MFMA-ize vspec (split vgate + vconv).
// B=4, H=W=256, C=32, heads=4, d=8. f32 I/O, fp32 accumulation, bf16 intermediates.
//
// R6 changes vs R5 (passed, 563us, absmax 0.015625):
//  - vspec_kernel (131us, MfmaUtil=0, VALUBusy 65%, 5.9M LDS bank conflicts, 28% halo
//    recompute of the V-projection) split into:
//      vgate_kernel: f32 V-proj + gate, each pixel exactly once, 2px/thread,
//                    writes gv bf16 [n][c] into the t_g slot (disjoint lifetime).
//      vconv_mfma_kernel: pos1-pattern conv3x3 via 9x2 mfma_f32_16x16x32_bf16,
//                    epilogue = +xhsi residual. No LDS.
//  - pre_kernel also repacks attnW -> [r][o][i] bf16 (wAv); in split mode wAv reuses
//    the wt1 slot (fallback layouts skipped via flag).
//  - Fallback (!split): R3/R4 vspec_kernel + pos_out_kernel, unchanged.

#define NB 4
#define NC 32
#define NS 256
#define NN 65536

typedef unsigned short u16;
typedef unsigned int u32;
typedef __bf16 bf16x8 __attribute__((ext_vector_type(8)));
typedef float f32x4 __attribute__((ext_vector_type(4)));

__device__ __forceinline__ float bf2f(u16 s){ return __uint_as_float(((u32)s) << 16); }
__device__ __forceinline__ u16 f2bf(float x){
  u32 u = __float_as_uint(x);
  u32 r = (u + 0x7fffu + ((u >> 16) & 1u)) >> 16;   // RNE
  return (u16)r;
}
__device__ __forceinline__ void dec8(uint4 u, float* f){
  f[0] = __uint_as_float((u.x & 0xffffu) << 16);
  f[1] = __uint_as_float(u.x & 0xffff0000u);
  f[2] = __uint_as_float((u.y & 0xffffu) << 16);
  f[3] = __uint_as_float(u.y & 0xffff0000u);
  f[4] = __uint_as_float((u.z & 0xffffu) << 16);
  f[5] = __uint_as_float(u.z & 0xffff0000u);
  f[6] = __uint_as_float((u.w & 0xffffu) << 16);
  f[7] = __uint_as_float(u.w & 0xffff0000u);
}
__device__ __forceinline__ void ld32f(const float* __restrict__ p, float* x){
  const float4* q = (const float4*)p;
  #pragma unroll
  for (int k = 0; k < 8; k++){
    float4 f = q[k];
    x[4 * k] = f.x; x[4 * k + 1] = f.y; x[4 * k + 2] = f.z; x[4 * k + 3] = f.w;
  }
}
__device__ __forceinline__ uint4 pack8(const float* f){
  uint4 u;
  u.x = (u32)f2bf(f[0]) | ((u32)f2bf(f[1]) << 16);
  u.y = (u32)f2bf(f[2]) | ((u32)f2bf(f[3]) << 16);
  u.z = (u32)f2bf(f[4]) | ((u32)f2bf(f[5]) << 16);
  u.w = (u32)f2bf(f[6]) | ((u32)f2bf(f[7]) << 16);
  return u;
}
__device__ __forceinline__ float gelu_exact(float x){
  return 0.5f * x * (1.0f + erff(x * 0.70710678118654752f));
}
__device__ __forceinline__ float sigmoidf_(float x){ return 1.0f / (1.0f + expf(-x)); }

// ---------------------- pre: zero accumulators + fold SA weights + transpose pos weights
__global__ __launch_bounds__(256) void pre_kernel(
    const float* __restrict__ c1a, const float* __restrict__ c1b,
    const float* __restrict__ c2a, const float* __restrict__ c2b,
    const float* __restrict__ p1, const float* __restrict__ p2,
    const float* __restrict__ aw,
    float* __restrict__ zbase, float* __restrict__ W1, float* __restrict__ W2,
    u16* __restrict__ wt1, u16* __restrict__ wt2,
    u16* __restrict__ wA1, u16* __restrict__ wA2,
    u16* __restrict__ wAv, int fb){
  int t = threadIdx.x;
  for (int i = t; i < 1408; i += 256) zbase[i] = 0.f;          // sums(128) + gacc(1280)
  for (int idx = t; idx < 288; idx += 256){                    // W1[r*32+j]
    int r = idx >> 5, j = idx & 31;
    float s = 0.f;
    for (int i = 0; i < 32; i++) s += c1b[i] * c1a[(i * 32 + j) * 9 + r];
    W1[idx] = s;
  }
  for (int idx = t; idx < 1568; idx += 256){                   // W2[r*32+j]
    int r = idx >> 5, j = idx & 31;
    float s = 0.f;
    for (int i = 0; i < 32; i++) s += c2b[i] * c2a[(i * 32 + j) * 49 + r];
    W2[idx] = s;
  }
  for (int idx = t; idx < 9216; idx += 256){                   // OIHW -> layouts
    int o = idx / 288;
    int rem = idx - o * 288;
    int i = rem / 9;
    int r = rem - i * 9;
    u16 w1v = f2bf(p1[idx]);
    u16 w2v = f2bf(p2[idx]);
    if (fb){
      wt1[(r * 32 + i) * 32 + o] = w1v;    // [r][i][o]  (fallback path only)
      wt2[(r * 32 + i) * 32 + o] = w2v;
    }
    wA1[(r * 32 + o) * 32 + i] = w1v;      // [r][o][i]  (MFMA A-fragments)
    wA2[(r * 32 + o) * 32 + i] = w2v;
    wAv[(r * 32 + o) * 32 + i] = f2bf(aw[idx]);
  }
}

// ---------------------------------------------------------------- channel sums
__global__ __launch_bounds__(256) void channel_sum_kernel(const float* __restrict__ xhsi,
                                                          float* __restrict__ sums){
  int b = blockIdx.x >> 6;
  int blk = blockIdx.x & 63;
  const float* p = xhsi + (size_t)b * NN * NC;
  int t = threadIdx.x;
  int base = blk * 32768;
  float acc = 0.f;
  for (int k = 0; k < 128; k++) acc += p[base + t + k * 256];
  __shared__ float red[256];
  red[t] = acc;
  __syncthreads();
  if (t < 32){
    float s = 0.f;
    #pragma unroll
    for (int k = 0; k < 8; k++) s += red[t + k * 32];     // channel of red[j] is j&31
    atomicAdd(&sums[b * 32 + t], s);
  }
}

// ----------------- mid: channel mask (sigmoid MLP) + attention softmax + M fold
__global__ __launch_bounds__(256) void mid_kernel(
    const float* __restrict__ sums, const float* __restrict__ fc1,
    const float* __restrict__ fc2, float* __restrict__ cmaskf, float* __restrict__ out_cm,
    const float* __restrict__ gacc, const float* __restrict__ projW, float* __restrict__ Mf,
    u16* __restrict__ Mbf){
  __shared__ float avg[NB][NC], hid[NB][NC];
  __shared__ float attn_s[16][64];
  int t = threadIdx.x;
  if (t < 128){
    int b = t >> 5, o = t & 31;
    avg[b][o] = sums[t] * (1.0f / 65536.0f);
  }
  __syncthreads();
  if (t < 128){
    int b = t >> 5, o = t & 31;
    float s = 0.f;
    for (int j = 0; j < 32; j++) s += fc1[o * 32 + j] * avg[b][j];
    hid[b][o] = fmaxf(s, 0.f);
  }
  // attention: softmax over normalized gram (independent of channel-mask path)
  if (t < 128){
    int bh = t >> 3, d = t & 7;   // bh = b*4+h
    int b = bh >> 2, h = bh & 3;
    const float* base = gacc + b * 320;
    int o = h * 8 + d;
    float nk = fmaxf(sqrtf(base[256 + o]), 1e-12f);
    float l[8];
    float mx = -1e30f;
    #pragma unroll
    for (int e = 0; e < 8; e++){
      float nq = fmaxf(sqrtf(base[288 + h * 8 + e]), 1e-12f);
      l[e] = base[o * 8 + e] / (nk * nq);
      mx = fmaxf(mx, l[e]);
    }
    float se = 0.f;
    #pragma unroll
    for (int e = 0; e < 8; e++){ l[e] = expf(l[e] - mx); se += l[e]; }
    float inv = 1.f / se;
    #pragma unroll
    for (int e = 0; e < 8; e++) attn_s[bh][d * 8 + e] = l[e] * inv;
  }
  __syncthreads();
  if (t < 128){
    int b = t >> 5, o = t & 31;
    float s2 = 0.f;
    for (int i = 0; i < 32; i++) s2 += fc2[o * 32 + i] * hid[b][i];
    float m = sigmoidf_(s2);
    cmaskf[t] = m;
    out_cm[t] = m;
  }
  for (int idx = t; idx < 4096; idx += 256){        // M[b][o][i]
    int b = idx >> 10, o = (idx >> 5) & 31, i = idx & 31;
    int hd = i >> 3, e = i & 7;
    float s = 0.f;
    #pragma unroll
    for (int d = 0; d < 8; d++)
      s += projW[o * 32 + hd * 8 + d] * attn_s[b * 4 + hd][d * 8 + e];
    Mf[idx] = s;
    Mbf[idx] = f2bf(s);
  }
}

// tile: [c8][xl][yl] uint4 (8 bf16 channels per uint4). 16x16 output px, halo 3.
__global__ __launch_bounds__(256) void spatial_mask_kernel(
    const float* __restrict__ xmsi, const float* __restrict__ W1, const float* __restrict__ W2,
    const float* __restrict__ sac3, float* __restrict__ out_sm){
  __shared__ uint4 tile[4][22][25];
  __shared__ float W1s[9 * 32], W2s[49 * 32];
  int t = threadIdx.x;
  int b = blockIdx.z;
  int x0 = blockIdx.x * 16, y0 = blockIdx.y * 16;
  for (int idx = t; idx < 9 * 32;  idx += 256) W1s[idx] = W1[idx];
  for (int idx = t; idx < 49 * 32; idx += 256) W2s[idx] = W2[idx];
  for (int p = t; p < 484; p += 256){
    int xl = p / 22, yl = p - xl * 22;
    int X = x0 - 3 + xl, Y = y0 - 3 + yl;
    uint4 u0, u1, u2, u3;
    if (X >= 0 && X < NS && Y >= 0 && Y < NS){
      float xr[32];
      ld32f(xmsi + ((size_t)b * NN + (size_t)Y * NS + X) * NC, xr);
      u0 = pack8(xr); u1 = pack8(xr + 8); u2 = pack8(xr + 16); u3 = pack8(xr + 24);
    } else {
      u0 = u1 = u2 = u3 = make_uint4(0, 0, 0, 0);
    }
    tile[0][xl][yl] = u0; tile[1][xl][yl] = u1; tile[2][xl][yl] = u2; tile[3][xl][yl] = u3;
  }
  __syncthreads();
  int j = t & 15, i = t >> 4;     // j: y (h), i: x (w)
  float m1 = 0.f, m2 = 0.f;
  for (int aw = 0; aw < 7; aw++){
    for (int ah = 0; ah < 7; ah++){
      const float* wr = &W2s[(aw * 7 + ah) * 32];
      float s = 0.f;
      #pragma unroll
      for (int c = 0; c < 4; c++){
        uint4 u = tile[c][i + aw][j + ah];
        float g[8]; dec8(u, g);
        #pragma unroll
        for (int k = 0; k < 8; k++) s += g[k] * wr[c * 8 + k];
      }
      m2 += s;
    }
  }
  for (int aw = 0; aw < 3; aw++){
    for (int ah = 0; ah < 3; ah++){
      const float* wr = &W1s[(aw * 3 + ah) * 32];
      float s = 0.f;
      #pragma unroll
      for (int c = 0; c < 4; c++){
        uint4 u = tile[c][i + aw + 2][j + ah + 2];
        float g[8]; dec8(u, g);
        #pragma unroll
        for (int k = 0; k < 8; k++) s += g[k] * wr[c * 8 + k];
      }
      m1 += s;
    }
  }
  float m = sac3[0] * m1 + sac3[1] * m2;
  float sg = sigmoidf_(m);
  int x = x0 + i, y = y0 + j;
  out_sm[(size_t)b * NN + (size_t)x * NS + y] = sg;   // (b,1,w,h): w-major
}

// ---------------------------------------------------- fused q/k projection + gram
__global__ __launch_bounds__(256) void qk_gram_kernel(const float* __restrict__ xfu,
                                                      const float* __restrict__ Wq,
                                                      const float* __restrict__ Wk,
                                                      float* __restrict__ gacc){
  int t = threadIdx.x;
  int wv = t >> 6, lane = t & 63;
  int role = lane >> 5;           // 0: q, 1: k
  int o = lane & 31;
  const float* W = role ? Wk : Wq;
  float w[32];
  ld32f(W + o * 32, w);
  float Gacc[8];
  #pragma unroll
  for (int e = 0; e < 8; e++) Gacc[e] = 0.f;
  float nrm = 0.f;
  int base = blockIdx.x * 512 + wv * 128;
  int b = blockIdx.x >> 7;        // 128 blocks per batch
  for (int r = 0; r < 128; r++){
    int row = base + r;
    float xr[32];
    ld32f(xfu + (size_t)row * NC, xr);
    float s = 0.f;
    #pragma unroll
    for (int i2 = 0; i2 < 32; i2++) s += xr[i2] * w[i2];
    nrm += s * s;
    #pragma unroll
    for (int e = 0; e < 8; e++){
      float qe = __shfl(s, (o & 24) + e, 64);   // q-lane of same head, same row
      Gacc[e] += s * qe;                        // meaningful on k-lanes only
    }
  }
  __shared__ float LG[4][32][8];
  __shared__ float Lk[4][32], Lq[4][32];
  if (role){
    #pragma unroll
    for (int e = 0; e < 8; e++) LG[wv][o][e] = Gacc[e];
    Lk[wv][o] = nrm;
  } else {
    Lq[wv][o] = nrm;
  }
  __syncthreads();
  {
    int oo = t >> 3, ee = t & 7;
    float s4 = LG[0][oo][ee] + LG[1][oo][ee] + LG[2][oo][ee] + LG[3][oo][ee];
    atomicAdd(&gacc[b * 320 + t], s4);
  }
  if (t < 32){
    atomicAdd(&gacc[b * 320 + 256 + t], Lk[0][t] + Lk[1][t] + Lk[2][t] + Lk[3][t]);
  } else if (t < 64){
    int oo = t - 32;
    atomicAdd(&gacc[b * 320 + 288 + oo], Lq[0][oo] + Lq[1][oo] + Lq[2][oo] + Lq[3][oo]);
  }
}

// ----------------------- R6 SPLIT: vgate — f32 V-proj + gate, 2 px/thread, no halo
__global__ __launch_bounds__(256) void vgate_kernel(
    const float* __restrict__ xfu, const float* __restrict__ Wv,
    const float* __restrict__ out_sm, const float* __restrict__ cmaskf,
    u16* __restrict__ gv){
  __shared__ alignas(16) float WvL[1024];       // [i][o]
  __shared__ float cml[NC];
  int t = threadIdx.x;
  int b = blockIdx.x >> 7;                      // 512 blocks: 128 per batch, 2 rows each
  int px0 = blockIdx.x * 512 + t;               // (X = t, Y = 2*(blk&127))
  int px1 = px0 + 256;                          // (X = t, Y+1)
  int X = t;
  int Y0 = (px0 >> 8) & 255;

  for (int idx = t; idx < 1024; idx += 256){
    int oo = idx >> 5, ii = idx & 31;
    WvL[ii * 32 + oo] = Wv[idx];                // Wv[o][i] -> [i][o]
  }
  if (t < 32) cml[t] = cmaskf[b * 32 + t];
  __syncthreads();

  float xr0[32], xr1[32];
  ld32f(xfu + (size_t)px0 * NC, xr0);
  ld32f(xfu + (size_t)px1 * NC, xr1);
  float sm0 = out_sm[(size_t)b * NN + (size_t)X * NS + Y0];
  float sm1 = out_sm[(size_t)b * NN + (size_t)X * NS + Y0 + 1];

  float vo0[32], vo1[32];
  #pragma unroll
  for (int q = 0; q < 32; q++){ vo0[q] = 0.f; vo1[q] = 0.f; }
  for (int i = 0; i < 32; i++){
    const float4* wr = (const float4*)&WvL[i * 32];
    float a0 = xr0[i], a1 = xr1[i];
    #pragma unroll
    for (int q = 0; q < 8; q++){
      float4 w4 = wr[q];
      vo0[4 * q]     += a0 * w4.x;  vo1[4 * q]     += a1 * w4.x;
      vo0[4 * q + 1] += a0 * w4.y;  vo1[4 * q + 1] += a1 * w4.y;
      vo0[4 * q + 2] += a0 * w4.z;  vo1[4 * q + 2] += a1 * w4.z;
      vo0[4 * q + 3] += a0 * w4.w;  vo1[4 * q + 3] += a1 * w4.w;
    }
  }
  float g0[32], g1[32];
  #pragma unroll
  for (int c = 0; c < 32; c++){
    float cm = cml[c];
    g0[c] = vo0[c] * sm0 * cm;
    g1[c] = vo1[c] * sm1 * cm;
  }
  uint4* d0 = (uint4*)(gv + (size_t)px0 * NC);
  uint4* d1 = (uint4*)(gv + (size_t)px1 * NC);
  d0[0] = pack8(g0);  d0[1] = pack8(g0 + 8);  d0[2] = pack8(g0 + 16);  d0[3] = pack8(g0 + 24);
  d1[0] = pack8(g1);  d1[1] = pack8(g1 + 8);  d1[2] = pack8(g1 + 16);  d1[3] = pack8(g1 + 24);
}

// ------------------- R6 SPLIT: vconv — pos1-pattern MFMA conv3x3 + xhsi residual
__global__ __launch_bounds__(256) void vconv_mfma_kernel(
    const u16* __restrict__ gv, const u16* __restrict__ wAv,
    const float* __restrict__ xhsi, u16* __restrict__ vspec_g){
  int t = threadIdx.x;
  int wv = t >> 6, l = t & 63;
  int lp = l & 15, lk = l >> 4;                 // fragment pixel / k-chunk
  int b = blockIdx.x >> 8, Y = blockIdx.x & 255;

  bf16x8 wf[9][2];
  #pragma unroll
  for (int r = 0; r < 9; r++){
    wf[r][0] = *(const bf16x8*)(wAv + ((r * 32 + lp) * 32 + lk * 8));
    wf[r][1] = *(const bf16x8*)(wAv + ((r * 32 + 16 + lp) * 32 + lk * 8));
  }

  const u16* src = gv + (size_t)b * NN * NC;
  const float* res = xhsi + (size_t)b * NN * NC;
  u16* dst = vspec_g + (size_t)b * NN * NC;

  for (int g = 0; g < 4; g++){
    int X0 = wv * 64 + g * 16;
    f32x4 acc0 = {0.f, 0.f, 0.f, 0.f};
    f32x4 acc1 = {0.f, 0.f, 0.f, 0.f};
    #pragma unroll
    for (int dh = -1; dh <= 1; dh++){
      int Yi = Y + dh;
      if ((unsigned)Yi < NS){                   // uniform skip = zero-pad rows
        const u16* row = src + (size_t)Yi * (NS * NC) + lk * 8;
        #pragma unroll
        for (int dw = -1; dw <= 1; dw++){
          int Xi = X0 + lp + dw;
          uint4 u = make_uint4(0, 0, 0, 0);
          if (dw == 0 || (unsigned)Xi < NS) u = *(const uint4*)(row + Xi * NC);
          bf16x8 bfr = __builtin_bit_cast(bf16x8, u);
          const int r = (dw + 1) * 3 + (dh + 1);
          acc0 = __builtin_amdgcn_mfma_f32_16x16x32_bf16(wf[r][0], bfr, acc0, 0, 0, 0);
          acc1 = __builtin_amdgcn_mfma_f32_16x16x32_bf16(wf[r][1], bfr, acc1, 0, 0, 0);
        }
      }
    }
    // D: col=lp=pixel, rows = lk*4+j (+16 for tile 1) = out channel; + residual
    size_t n = (size_t)Y * NS + (X0 + lp);
    float4 rA = *(const float4*)(res + n * NC + lk * 4);
    float4 rB = *(const float4*)(res + n * NC + lk * 4 + 16);
    float v0 = acc0.x + rA.x;
    float v1 = acc0.y + rA.y;
    float v2 = acc0.z + rA.z;
    float v3 = acc0.w + rA.w;
    float v4 = acc1.x + rB.x;
    float v5 = acc1.y + rB.y;
    float v6 = acc1.z + rB.z;
    float v7 = acc1.w + rB.w;
    u16* dp = dst + n * NC + lk * 4;
    *(uint2*)dp = make_uint2((u32)f2bf(v0) | ((u32)f2bf(v1) << 16),
                             (u32)f2bf(v2) | ((u32)f2bf(v3) << 16));
    *(uint2*)(dp + 16) = make_uint2((u32)f2bf(v4) | ((u32)f2bf(v5) << 16),
                                    (u32)f2bf(v6) | ((u32)f2bf(v7) << 16));
  }
}

// ---------------- FALLBACK: fused V-proj + gate + conv + residual (R4, proven)
__global__ __launch_bounds__(256) void vspec_kernel(
    const float* __restrict__ xfu, const float* __restrict__ Wv,
    const float* __restrict__ attnW, const float* __restrict__ out_sm,
    const float* __restrict__ cmaskf, const float* __restrict__ xhsi,
    u16* __restrict__ vspec_g){
  __shared__ u16 gv[32 * 10 * 40];              // [c][xl][yl(34,pad40)] gated v, bf16
  __shared__ u16 Wl[9 * 32 * 32];               // [r][i][o] bf16, r = aw*3+ah
  __shared__ alignas(16) float WvL[1024];       // [i][o]
  __shared__ float cml[32];
  int t = threadIdx.x;
  int b = blockIdx.z;
  int x0 = blockIdx.x * 8, y0 = blockIdx.y * 32;

  for (int idx = t; idx < 1024; idx += 256){
    int oo = idx >> 5, ii = idx & 31;
    WvL[ii * 32 + oo] = Wv[idx];                // Wv[o][i] -> [i][o]
  }
  if (t < 32) cml[t] = cmaskf[b * 32 + t];
  __syncthreads();

  for (int idx = t; idx < 9216; idx += 256){
    int oo = idx / 288;
    int rem = idx - oo * 288;
    int ii = rem / 9;
    int r = rem - ii * 9;
    Wl[(r * 32 + ii) * 32 + oo] = f2bf(attnW[idx]);
  }
  for (int p = t; p < 340; p += 256){           // 10 x 34 halo tile
    int xl = p / 34, yl = p - xl * 34;
    int X = x0 - 1 + xl, Y = y0 - 1 + yl;       // X: w, Y: h
    u16* dst = &gv[xl * 40 + yl];               // + c*400 per channel
    if (X >= 0 && X < NS && Y >= 0 && Y < NS){
      float xr[32];
      ld32f(xfu + ((size_t)b * NN + (size_t)Y * NS + X) * NC, xr);
      float sm = out_sm[(size_t)b * NN + (size_t)X * NS + Y];
      float vo[32];
      #pragma unroll
      for (int q = 0; q < 32; q++) vo[q] = 0.f;
      for (int i = 0; i < 32; i++){
        const float4* wr = (const float4*)&WvL[i * 32];
        float xv = xr[i];
        #pragma unroll
        for (int q = 0; q < 8; q++){
          float4 w4 = wr[q];
          vo[4 * q]     += xv * w4.x;
          vo[4 * q + 1] += xv * w4.y;
          vo[4 * q + 2] += xv * w4.z;
          vo[4 * q + 3] += xv * w4.w;
        }
      }
      #pragma unroll
      for (int c = 0; c < 32; c++) dst[c * 400] = f2bf(vo[c] * sm * cml[c]);
    } else {
      #pragma unroll
      for (int c = 0; c < 32; c++) dst[c * 400] = 0;
    }
  }
  __syncthreads();

  int o = t & 31, xs = t >> 5;
  float acc[32];
  #pragma unroll
  for (int yy = 0; yy < 32; yy++) acc[yy] = 0.f;
  #pragma unroll
  for (int aw = 0; aw < 3; aw++){
    for (int i2 = 0; i2 < 32; i2++){
      const uint4* rp = (const uint4*)(gv + (i2 * 10 + xs + aw) * 40);
      uint4 r0 = rp[0], r1 = rp[1], r2 = rp[2], r3 = rp[3], r4 = rp[4];
      float g[40];
      dec8(r0, g); dec8(r1, g + 8); dec8(r2, g + 16); dec8(r3, g + 24); dec8(r4, g + 32);
      const int wb = (aw * 3 * 32 + i2) * 32 + o;
      float w0 = bf2f(Wl[wb]);
      float w1 = bf2f(Wl[wb + 1024]);
      float w2 = bf2f(Wl[wb + 2048]);
      #pragma unroll
      for (int yy = 0; yy < 32; yy++)
        acc[yy] = fmaf(g[yy], w0, fmaf(g[yy + 1], w1, fmaf(g[yy + 2], w2, acc[yy])));
    }
  }
  int x = x0 + xs;
  #pragma unroll
  for (int yy = 0; yy < 32; yy++){
    size_t n = (size_t)b * NN + (size_t)(y0 + yy) * NS + x;
    vspec_g[n * NC + o] = f2bf(acc[yy] + xhsi[n * NC + o]);
  }
}

// ------------------------- SPLIT PATH R5: MFMA pos1 (vspec -> t), no LDS
// Wave handles 4 groups of 16 consecutive X at fixed Y. A=W[r][o][i], B=vspec px.
__global__ __launch_bounds__(256) void pos1_mfma_kernel(
    const u16* __restrict__ vspec_g, const u16* __restrict__ wA,
    const float* __restrict__ pos1b, u16* __restrict__ t_g){
  int t = threadIdx.x;
  int wv = t >> 6, l = t & 63;
  int lp = l & 15, lk = l >> 4;                 // fragment pixel / k-chunk
  int b = blockIdx.x >> 8, Y = blockIdx.x & 255;

  bf16x8 wf[9][2];
  #pragma unroll
  for (int r = 0; r < 9; r++){
    wf[r][0] = *(const bf16x8*)(wA + ((r * 32 + lp) * 32 + lk * 8));
    wf[r][1] = *(const bf16x8*)(wA + ((r * 32 + 16 + lp) * 32 + lk * 8));
  }
  float bs[8];
  #pragma unroll
  for (int j = 0; j < 4; j++){
    bs[j]     = pos1b[lk * 4 + j];
    bs[4 + j] = pos1b[16 + lk * 4 + j];
  }

  const u16* src = vspec_g + (size_t)b * NN * NC;
  u16* dst = t_g + (size_t)b * NN * NC;

  for (int g = 0; g < 4; g++){
    int X0 = wv * 64 + g * 16;
    f32x4 acc0 = {0.f, 0.f, 0.f, 0.f};
    f32x4 acc1 = {0.f, 0.f, 0.f, 0.f};
    #pragma unroll
    for (int dh = -1; dh <= 1; dh++){
      int Yi = Y + dh;
      if ((unsigned)Yi < NS){                   // uniform skip = zero-pad rows
        const u16* row = src + (size_t)Yi * (NS * NC) + lk * 8;
        #pragma unroll
        for (int dw = -1; dw <= 1; dw++){
          int Xi = X0 + lp + dw;
          uint4 u = make_uint4(0, 0, 0, 0);
          if (dw == 0 || (unsigned)Xi < NS) u = *(const uint4*)(row + Xi * NC);
          bf16x8 bfr = __builtin_bit_cast(bf16x8, u);
          const int r = (dw + 1) * 3 + (dh + 1);
          acc0 = __builtin_amdgcn_mfma_f32_16x16x32_bf16(wf[r][0], bfr, acc0, 0, 0, 0);
          acc1 = __builtin_amdgcn_mfma_f32_16x16x32_bf16(wf[r][1], bfr, acc1, 0, 0, 0);
        }
      }
    }
    // D: col=lp=pixel, rows = lk*4+j (+16 for tile 1) = out channel
    float v0 = gelu_exact(acc0.x + bs[0]);
    float v1 = gelu_exact(acc0.y + bs[1]);
    float v2 = gelu_exact(acc0.z + bs[2]);
    float v3 = gelu_exact(acc0.w + bs[3]);
    float v4 = gelu_exact(acc1.x + bs[4]);
    float v5 = gelu_exact(acc1.y + bs[5]);
    float v6 = gelu_exact(acc1.z + bs[6]);
    float v7 = gelu_exact(acc1.w + bs[7]);
    u16* dp = dst + ((size_t)Y * NS + (X0 + lp)) * NC + lk * 4;
    *(uint2*)dp = make_uint2((u32)f2bf(v0) | ((u32)f2bf(v1) << 16),
                             (u32)f2bf(v2) | ((u32)f2bf(v3) << 16));
    *(uint2*)(dp + 16) = make_uint2((u32)f2bf(v4) | ((u32)f2bf(v5) << 16),
                                    (u32)f2bf(v6) | ((u32)f2bf(v7) << 16));
  }
}

// -------------------- SPLIT PATH R5: MFMA pos2 (t -> out, + out1 epilogue), no LDS
// Wave handles 4 groups of 16 consecutive Y at fixed X (store (b,c,w,h) coalesced in h).
__global__ __launch_bounds__(256) void pos2_mfma_kernel(
    const u16* __restrict__ t_g, const u16* __restrict__ vspec_g,
    const u16* __restrict__ wA, const float* __restrict__ pos2b,
    const u16* __restrict__ Mbf, const float* __restrict__ projb,
    float* __restrict__ outp){
  int t = threadIdx.x;
  int wv = t >> 6, l = t & 63;
  int lp = l & 15, lk = l >> 4;
  int b = blockIdx.x >> 8, X = blockIdx.x & 255;

  bf16x8 wf[9][2];
  #pragma unroll
  for (int r = 0; r < 9; r++){
    wf[r][0] = *(const bf16x8*)(wA + ((r * 32 + lp) * 32 + lk * 8));
    wf[r][1] = *(const bf16x8*)(wA + ((r * 32 + 16 + lp) * 32 + lk * 8));
  }
  bf16x8 mf0 = *(const bf16x8*)(Mbf + ((b * 32 + lp) * 32 + lk * 8));
  bf16x8 mf1 = *(const bf16x8*)(Mbf + ((b * 32 + 16 + lp) * 32 + lk * 8));
  float b2s[8], pbs[8];
  #pragma unroll
  for (int j = 0; j < 4; j++){
    b2s[j]     = pos2b[lk * 4 + j];
    b2s[4 + j] = pos2b[16 + lk * 4 + j];
    pbs[j]     = projb[lk * 4 + j];
    pbs[4 + j] = projb[16 + lk * 4 + j];
  }

  const u16* tsrc = t_g + (size_t)b * NN * NC;
  const u16* vsrc = vspec_g + (size_t)b * NN * NC;
  float* ob0 = outp + (size_t)b * 32 * NN + (size_t)X * NS;

  for (int g = 0; g < 4; g++){
    int Y0 = wv * 64 + g * 16;
    int Yp = Y0 + lp;
    // epilogue GEMM first (independent chain): P = M @ vspec[px]
    f32x4 e0 = {0.f, 0.f, 0.f, 0.f};
    f32x4 e1 = {0.f, 0.f, 0.f, 0.f};
    {
      uint4 u = *(const uint4*)(vsrc + ((size_t)Yp * NS + X) * NC + lk * 8);
      bf16x8 bfr = __builtin_bit_cast(bf16x8, u);
      e0 = __builtin_amdgcn_mfma_f32_16x16x32_bf16(mf0, bfr, e0, 0, 0, 0);
      e1 = __builtin_amdgcn_mfma_f32_16x16x32_bf16(mf1, bfr, e1, 0, 0, 0);
    }
    f32x4 acc0 = {0.f, 0.f, 0.f, 0.f};
    f32x4 acc1 = {0.f, 0.f, 0.f, 0.f};
    #pragma unroll
    for (int dw = -1; dw <= 1; dw++){
      int Xi = X + dw;
      if ((unsigned)Xi < NS){                   // uniform skip = zero-pad cols
        const u16* col = tsrc + (size_t)Xi * NC + lk * 8;
        #pragma unroll
        for (int dh = -1; dh <= 1; dh++){
          int Yi = Yp + dh;
          uint4 u = make_uint4(0, 0, 0, 0);
          if (dh == 0 || (unsigned)Yi < NS) u = *(const uint4*)(col + (size_t)Yi * (NS * NC));
          bf16x8 bfr = __builtin_bit_cast(bf16x8, u);
          const int r = (dw + 1) * 3 + (dh + 1);
          acc0 = __builtin_amdgcn_mfma_f32_16x16x32_bf16(wf[r][0], bfr, acc0, 0, 0, 0);
          acc1 = __builtin_amdgcn_mfma_f32_16x16x32_bf16(wf[r][1], bfr, acc1, 0, 0, 0);
        }
      }
    }
    float r0 = acc0.x + b2s[0] + gelu_exact(e0.x + pbs[0]);
    float r1 = acc0.y + b2s[1] + gelu_exact(e0.y + pbs[1]);
    float r2 = acc0.z + b2s[2] + gelu_exact(e0.z + pbs[2]);
    float r3 = acc0.w + b2s[3] + gelu_exact(e0.w + pbs[3]);
    float r4 = acc1.x + b2s[4] + gelu_exact(e1.x + pbs[4]);
    float r5 = acc1.y + b2s[5] + gelu_exact(e1.y + pbs[5]);
    float r6 = acc1.z + b2s[6] + gelu_exact(e1.z + pbs[6]);
    float r7 = acc1.w + b2s[7] + gelu_exact(e1.w + pbs[7]);
    float* ob = ob0 + Yp + (size_t)(lk * 4) * NN;   // channel lk*4, + c*NN per channel
    ob[0]                 = r0;
    ob[(size_t)NN]        = r1;
    ob[(size_t)2 * NN]    = r2;
    ob[(size_t)3 * NN]    = r3;
    float* ob2 = ob + (size_t)16 * NN;
    ob2[0]                = r4;
    ob2[(size_t)NN]       = r5;
    ob2[(size_t)2 * NN]   = r6;
    ob2[(size_t)3 * NN]   = r7;
  }
}

// ------------------------- FALLBACK PATH (ws too small): R3's fused pos_out, proven
__global__ __launch_bounds__(320) void pos_out_kernel(
    const u16* __restrict__ vspec_g, const u16* __restrict__ wt1,
    const u16* __restrict__ wt2, const float* __restrict__ pos1b,
    const float* __restrict__ pos2b, const float* __restrict__ Mf,
    const float* __restrict__ projb, float* __restrict__ outp){
  __shared__ u16 vs[32 * 12 * 40];    // [i][vxl(12)][vyl(36,pad40)]
  __shared__ u16 tt[32 * 10 * 40];    // [o][txl(10)][tyl(34,pad40)]
  __shared__ u16 wsl[3072];           // one aw-slice: [ah][i][o]
  int t = threadIdx.x;
  int b = blockIdx.z;
  int x0 = blockIdx.x * 8, y0 = blockIdx.y * 32;
  int o = t & 31, xsl = t >> 5;       // xsl in [0,10)

  for (int p = t; p < 12 * 36; p += 320){
    int vxl = p / 36, vyl = p - vxl * 36;
    int X = x0 - 2 + vxl, Y = y0 - 2 + vyl;
    u16* dst = &vs[vxl * 40 + vyl];
    if (X >= 0 && X < NS && Y >= 0 && Y < NS){
      const uint4* src = (const uint4*)(vspec_g + ((size_t)b * NN + (size_t)Y * NS + X) * NC);
      uint4 u0 = src[0], u1 = src[1], u2 = src[2], u3 = src[3];
      alignas(16) u16 raw[32];
      *(uint4*)(raw) = u0; *(uint4*)(raw + 8) = u1;
      *(uint4*)(raw + 16) = u2; *(uint4*)(raw + 24) = u3;
      #pragma unroll
      for (int i = 0; i < 32; i++) dst[i * 480] = raw[i];
    } else {
      #pragma unroll
      for (int i = 0; i < 32; i++) dst[i * 480] = 0;
    }
  }
  __syncthreads();

  float ta[34];
  #pragma unroll
  for (int k = 0; k < 34; k++) ta[k] = 0.f;
  for (int aw = 0; aw < 3; aw++){
    for (int idx = t; idx < 3072; idx += 320) wsl[idx] = wt1[aw * 3072 + idx];
    __syncthreads();
    for (int i2 = 0; i2 < 32; i2++){
      const uint4* rp = (const uint4*)(vs + (i2 * 12 + xsl + aw) * 40);
      uint4 r0 = rp[0], r1 = rp[1], r2 = rp[2], r3 = rp[3], r4 = rp[4];
      float g[40];
      dec8(r0, g); dec8(r1, g + 8); dec8(r2, g + 16); dec8(r3, g + 24); dec8(r4, g + 32);
      float w0 = bf2f(wsl[i2 * 32 + o]);
      float w1 = bf2f(wsl[i2 * 32 + o + 1024]);
      float w2 = bf2f(wsl[i2 * 32 + o + 2048]);
      #pragma unroll
      for (int yl = 0; yl < 34; yl++)
        ta[yl] = fmaf(g[yl], w0, fmaf(g[yl + 1], w1, fmaf(g[yl + 2], w2, ta[yl])));
    }
    __syncthreads();
  }
  {
    float b1 = pos1b[o];
    int X = x0 - 1 + xsl;
    bool colOK = (X >= 0 && X < NS);
    u16* trow = &tt[(o * 10 + xsl) * 40];
    #pragma unroll
    for (int yl = 0; yl < 34; yl++){
      int Y = y0 - 1 + yl;
      float val = (colOK && Y >= 0 && Y < NS) ? gelu_exact(ta[yl] + b1) : 0.f;
      trow[yl] = f2bf(val);
    }
  }
  __syncthreads();

  float acc2[32];
  #pragma unroll
  for (int yy = 0; yy < 32; yy++) acc2[yy] = 0.f;
  for (int aw = 0; aw < 3; aw++){
    for (int idx = t; idx < 3072; idx += 320) wsl[idx] = wt2[aw * 3072 + idx];
    __syncthreads();
    if (xsl < 8){
      for (int i2 = 0; i2 < 32; i2++){
        const uint4* rp = (const uint4*)(tt + (i2 * 10 + xsl + aw) * 40);
        uint4 r0 = rp[0], r1 = rp[1], r2 = rp[2], r3 = rp[3], r4 = rp[4];
        float g[40];
        dec8(r0, g); dec8(r1, g + 8); dec8(r2, g + 16); dec8(r3, g + 24); dec8(r4, g + 32);
        float w0 = bf2f(wsl[i2 * 32 + o]);
        float w1 = bf2f(wsl[i2 * 32 + o + 1024]);
        float w2 = bf2f(wsl[i2 * 32 + o + 2048]);
        #pragma unroll
        for (int yy = 0; yy < 32; yy++)
          acc2[yy] = fmaf(g[yy], w0, fmaf(g[yy + 1], w1, fmaf(g[yy + 2], w2, acc2[yy])));
      }
    }
    __syncthreads();
  }
  if (xsl < 8){
    int x = x0 + xsl;
    float m[32];
    {
      const float4* mp = (const float4*)(Mf + b * 1024 + o * 32);
      #pragma unroll
      for (int k = 0; k < 8; k++){
        float4 f = mp[k];
        m[4 * k] = f.x; m[4 * k + 1] = f.y; m[4 * k + 2] = f.z; m[4 * k + 3] = f.w;
      }
    }
    float pb = projb[o];
    float b2v = pos2b[o];
    float outv[32];
    #pragma unroll
    for (int yy = 0; yy < 32; yy++){
      size_t n = (size_t)b * NN + (size_t)(y0 + yy) * NS + x;
      const uint4* xp = (const uint4*)(vspec_g + n * NC);
      uint4 u0 = xp[0], u1 = xp[1], u2 = xp[2], u3 = xp[3];
      float xr[32];
      dec8(u0, xr); dec8(u1, xr + 8); dec8(u2, xr + 16); dec8(u3, xr + 24);
      float s = pb;
      #pragma unroll
      for (int i2 = 0; i2 < 32; i2++) s += m[i2] * xr[i2];
      outv[yy] = acc2[yy] + b2v + gelu_exact(s);
    }
    float4* dp = (float4*)(outp + (((size_t)(b * 32 + o) * NS) + x) * NS + y0);
    #pragma unroll
    for (int k = 0; k < 8; k++)
      dp[k] = make_float4(outv[4 * k], outv[4 * k + 1], outv[4 * k + 2], outv[4 * k + 3]);
  }
}

// ---------------------------------------------------------------------- launch
extern "C" void kernel_launch(void* const* d_in, const int* in_sizes, int n_in,
                              void* d_out, int out_size, void* d_ws, size_t ws_size,
                              hipStream_t stream){
  (void)in_sizes; (void)n_in; (void)out_size;
  const float* xfu   = (const float*)d_in[0];
  const float* xmsi  = (const float*)d_in[1];
  const float* xhsi  = (const float*)d_in[2];
  const float* Wq    = (const float*)d_in[3];
  const float* Wk    = (const float*)d_in[4];
  const float* Wv    = (const float*)d_in[5];
  const float* projW = (const float*)d_in[6];
  const float* projb = (const float*)d_in[7];
  const float* pos1W = (const float*)d_in[8];
  const float* pos1b = (const float*)d_in[9];
  const float* pos2W = (const float*)d_in[10];
  const float* pos2b = (const float*)d_in[11];
  const float* cafc1 = (const float*)d_in[12];
  const float* cafc2 = (const float*)d_in[13];
  const float* sac1a = (const float*)d_in[14];
  const float* sac1b = (const float*)d_in[15];
  const float* sac2a = (const float*)d_in[16];
  const float* sac2b = (const float*)d_in[17];
  const float* sac3  = (const float*)d_in[18];
  const float* attnW = (const float*)d_in[19];

  float* out = (float*)d_out;
  float* out_main = out;                  // (b,c,w,h) 8388608 f32
  float* out_cm   = out + 8388608;        // 128
  float* out_sm   = out + 8388736;        // 262144

  // workspace map: small [0,32K), wt/wAv [32K,70K), wA/Mbf [70K,115K),
  // vspec [128K,+16M), t/gv [+16M,+32M)  (gv aliases t_g: disjoint lifetimes)
  char* ws = (char*)d_ws;
  float* sums   = (float*)(ws + 0);         // 128 f   (zeroed with gacc: 1408 f total)
  float* gacc   = (float*)(ws + 512);       // 1280 f
  float* cmaskf = (float*)(ws + 5632);      // 128 f
  float* W1     = (float*)(ws + 6144);      // 288 f
  float* W2     = (float*)(ws + 7296);      // 1568 f
  float* Mf     = (float*)(ws + 16384);     // 4096 f
  u16*   wt1    = (u16*)(ws + 32768);       // 9216 bf16 [r][i][o] (fallback) / wAv (split)
  u16*   wt2    = (u16*)(ws + 51200);       // 9216 bf16
  u16*   wA1    = (u16*)(ws + 69632);       // 9216 bf16 [r][o][i] (MFMA)
  u16*   wA2    = (u16*)(ws + 88064);       // 9216 bf16
  u16*   Mbf    = (u16*)(ws + 106496);      // 4096 bf16 [b][o][i]
  u16*   vspec  = (u16*)(ws + 131072);      // 16 MB bf16 (b,n,c)
  u16*   t_g    = (u16*)(ws + 131072 + 16777216);   // 16 MB bf16 (split path only)
  const bool split = ws_size >= (size_t)(131072 + 2 * 16777216);
  u16*   wAv    = split ? wt1 : wA1;        // split: wt1 slot free; fallback: dummy
  u16*   gvbuf  = t_g;                      // gv dies before pos1 writes t_g

  pre_kernel<<<1, 256, 0, stream>>>(sac1a, sac1b, sac2a, sac2b, pos1W, pos2W, attnW,
                                    sums, W1, W2, wt1, wt2, wA1, wA2, wAv,
                                    split ? 0 : 1);
  channel_sum_kernel<<<256, 256, 0, stream>>>(xhsi, sums);
  spatial_mask_kernel<<<dim3(16, 16, NB), 256, 0, stream>>>(xmsi, W1, W2, sac3, out_sm);
  qk_gram_kernel<<<512, 256, 0, stream>>>(xfu, Wq, Wk, gacc);
  mid_kernel<<<1, 256, 0, stream>>>(sums, cafc1, cafc2, cmaskf, out_cm, gacc, projW, Mf, Mbf);
  if (split){
    vgate_kernel<<<512, 256, 0, stream>>>(xfu, Wv, out_sm, cmaskf, gvbuf);
    vconv_mfma_kernel<<<1024, 256, 0, stream>>>(gvbuf, wAv, xhsi, vspec);
    pos1_mfma_kernel<<<1024, 256, 0, stream>>>(vspec, wA1, pos1b, t_g);
    pos2_mfma_kernel<<<1024, 256, 0, stream>>>(t_g, vspec, wA2, pos2b, Mbf, projb, out_main);
  } else {
    vspec_kernel<<<dim3(32, 8, NB), 256, 0, stream>>>(
        xfu, Wv, attnW, out_sm, cmaskf, xhsi, vspec);
    pos_out_kernel<<<dim3(32, 8, NB), 320, 0, stream>>>(
        vspec, wt1, wt2, pos1b, pos2b, Mf, projb, out_main);
  }
}